// Round 2
// 319.569 us; speedup vs baseline: 1.3583x; 1.3583x over previous
//
#include <hip/hip_runtime.h>
#include <stdint.h>

#define DD 160
#define HH 160
#define WW 160
#define NGRID (DD*HH*WW)
#define CIN 32
#define COUT 64
#define KK 27
#define BLOCK 1024
#define WPB 16          // waves per block
#define NBLOCKS 256
#define M27 0x07FFFFFFu

typedef _Float16 h2_t __attribute__((ext_vector_type(2)));

__device__ __forceinline__ h2_t as_h2(uint32_t u) {
    union { uint32_t u; h2_t h; } c; c.u = u; return c.h;
}
__device__ __forceinline__ uint32_t f2h(float f) {
    union { _Float16 h; uint16_t u; } c; c.h = (_Float16)f; return (uint32_t)c.u;
}

// 2-wide f16 dot with f32 accumulate: v_dot2_f32_f16
__device__ __forceinline__ float dot2(uint32_t fu, uint32_t wu, float acc) {
#if defined(__has_builtin)
#if __has_builtin(__builtin_amdgcn_fdot2)
    return __builtin_amdgcn_fdot2(as_h2(fu), as_h2(wu), acc, false);
#else
    h2_t f = as_h2(fu), w = as_h2(wu);
    acc = fmaf((float)f.x, (float)w.x, acc);
    return fmaf((float)f.y, (float)w.y, acc);
#endif
#else
    h2_t f = as_h2(fu), w = as_h2(wu);
    acc = fmaf((float)f.x, (float)w.x, acc);
    return fmaf((float)f.y, (float)w.y, acc);
#endif
}

__global__ void scatter_grid(const int4* __restrict__ coors, int* __restrict__ grid, int n) {
    int i = blockIdx.x * 256 + threadIdx.x;
    if (i < n) {
        int4 c = coors[i];
        grid[(c.y*HH + c.z)*WW + c.w] = i;
    }
}

// weight f32 [k][ci][co] -> packed f16 uint4 [k][g][co]  (g = ci/8, 8 cin per uint4)
__global__ void pack_weights(const float* __restrict__ w, uint4* __restrict__ wpk) {
    int t = blockIdx.x * 256 + threadIdx.x;
    if (t >= KK*4*COUT) return;
    int co = t & 63;
    int g  = (t >> 6) & 3;
    int k  = t >> 8;
    const float* base = w + (size_t)k*CIN*COUT + (size_t)(8*g)*COUT + co;
    uint4 r;
    r.x = f2h(base[0*COUT]) | (f2h(base[1*COUT]) << 16);
    r.y = f2h(base[2*COUT]) | (f2h(base[3*COUT]) << 16);
    r.z = f2h(base[4*COUT]) | (f2h(base[5*COUT]) << 16);
    r.w = f2h(base[6*COUT]) | (f2h(base[7*COUT]) << 16);
    wpk[t] = r;
}

// features f32 -> packed f16 (2 per uint32), row = 32 f16 = 64B = 4 uint4
__global__ void feats_to_h(const float4* __restrict__ f, uint2* __restrict__ o, int nq) {
    int i = blockIdx.x * 256 + threadIdx.x;
    if (i < nq) {
        float4 v = f[i];
        uint2 r;
        r.x = f2h(v.x) | (f2h(v.y) << 16);
        r.y = f2h(v.z) | (f2h(v.w) << 16);
        o[i] = r;
    }
}

// load 4x uint4 (32 f16 feats) broadcast from voxel j = readlane(nidx, base+kk)
#define LOAD4(D0,D1,D2,D3,kk) { \
    int j_ = __builtin_amdgcn_readlane(nidx, base + (kk)); \
    const uint4* fp_ = fh4 + (size_t)j_ * 4; \
    D0 = fp_[0]; D1 = fp_[1]; D2 = fp_[2]; D3 = fp_[3]; }

// 16 v_dot2_f32_f16 against LDS weights for tap kk
#define MAC4(F0,F1,F2,F3,kk) { \
    const uint4* wl_ = wlds + (size_t)(kk)*4*COUT + lane; \
    uint4 w0_ = wl_[0], w1_ = wl_[COUT], w2_ = wl_[2*COUT], w3_ = wl_[3*COUT]; \
    a0 = dot2(F0.x, w0_.x, a0); a1 = dot2(F0.y, w0_.y, a1); \
    a2 = dot2(F0.z, w0_.z, a2); a3 = dot2(F0.w, w0_.w, a3); \
    a0 = dot2(F1.x, w1_.x, a0); a1 = dot2(F1.y, w1_.y, a1); \
    a2 = dot2(F1.z, w1_.z, a2); a3 = dot2(F1.w, w1_.w, a3); \
    a0 = dot2(F2.x, w2_.x, a0); a1 = dot2(F2.y, w2_.y, a1); \
    a2 = dot2(F2.z, w2_.z, a2); a3 = dot2(F2.w, w2_.w, a3); \
    a0 = dot2(F3.x, w3_.x, a0); a1 = dot2(F3.y, w3_.y, a1); \
    a2 = dot2(F3.z, w3_.z, a2); a3 = dot2(F3.w, w3_.w, a3); }

// one wave handles a PAIR of voxels per probe round:
// lanes 0..26 probe voxel v, lanes 32..58 probe voxel v+stride (one ballot).
__global__ __launch_bounds__(BLOCK, 4) void sparse_conv(
    const uint4* __restrict__ fh4, const int4* __restrict__ cc,
    const float* __restrict__ bias, const uint4* __restrict__ wpk,
    const int* __restrict__ grid, float* __restrict__ out, int n)
{
    extern __shared__ uint4 wlds[];   // [KK*4*COUT] = 110,592 B

    for (int t = threadIdx.x; t < KK*4*COUT; t += BLOCK)
        wlds[t] = wpk[t];
    __syncthreads();

    const int lane = threadIdx.x & 63;
    const int wave = __builtin_amdgcn_readfirstlane((int)(threadIdx.x >> 6));
    const int stride = NBLOCKS * WPB;       // 4096
    const int pairstep = 2 * stride;        // 8192

    const float b = bias[lane];
    const int pl = lane & 31;
    const bool prober = pl < KK;
    const int dz = pl / 9 - 1;
    const int dy = (pl / 3) % 3 - 1;
    const int dx = pl % 3 - 1;
    const int hioff = (lane >= 32) ? stride : 0;

    int v = blockIdx.x * WPB + wave;
    int nidx = -1;   // declared BEFORE the lambdas so [&] capture binds it

    auto probe = [&](int pb) -> int {
        int r = -1;
        int pv = pb + hioff;
        if (prober && pv < n) {
            int4 c = cc[pv];
            int nz = c.y + dz, ny = c.z + dy, nx = c.w + dx;
            if (nz >= 0 && nz < DD && ny >= 0 && ny < HH && nx >= 0 && nx < WW)
                r = grid[(nz*HH + ny)*WW + nx];
        }
        return r;
    };

    auto runvox = [&](uint32_t m, int base, int vo) {
        float a0 = 0.f, a1 = 0.f, a2 = 0.f, a3 = 0.f;
        uint4 A0, A1, A2, A3, B0, B1, B2, B3;
        int kA = __ffs(m) - 1; m &= m - 1;
        LOAD4(A0, A1, A2, A3, kA);
        for (;;) {
            if (!m) { MAC4(A0, A1, A2, A3, kA); break; }
            int kB = __ffs(m) - 1; m &= m - 1;
            LOAD4(B0, B1, B2, B3, kB);         // prefetch next tap
            MAC4(A0, A1, A2, A3, kA);          // compute current tap
            if (!m) { MAC4(B0, B1, B2, B3, kB); break; }
            kA = __ffs(m) - 1; m &= m - 1;
            LOAD4(A0, A1, A2, A3, kA);
            MAC4(B0, B1, B2, B3, kB);
        }
        float r = b + ((a0 + a1) + (a2 + a3));
        __builtin_nontemporal_store(r, out + (size_t)vo * COUT + lane);
    };

    nidx = probe(v);

    while (v < n) {
        unsigned long long bal = __ballot(nidx >= 0);
        // issue next pair's probe before the MAC phase (latency hidden under dot2s)
        int nidx_next = probe(v + pairstep);

        uint32_t m0 = (uint32_t)bal & M27;            // voxel v taps (self bit 13 always set)
        uint32_t m1 = (uint32_t)(bal >> 32) & M27;    // voxel v+stride taps

        {
            // runvox reads `nidx` via readlane inside LOAD4
            int saved = nidx;
            runvox(m0, 0, v);
            int vB = v + stride;
            if (vB < n) runvox(m1, 32, vB);
            nidx = saved;
        }

        v += pairstep;
        nidx = nidx_next;
    }
}

extern "C" void kernel_launch(void* const* d_in, const int* in_sizes, int n_in,
                              void* d_out, int out_size, void* d_ws, size_t ws_size,
                              hipStream_t stream) {
    const float* feats  = (const float*)d_in[0];
    const int*   coors  = (const int*)d_in[1];
    const float* weight = (const float*)d_in[2];
    const float* bias   = (const float*)d_in[3];
    float*       outp   = (float*)d_out;

    const int n = in_sizes[1] / 4;   // 400000

    int*   grid = (int*)d_ws;
    uint4* wpk  = (uint4*)((char*)d_ws + (size_t)NGRID * sizeof(int));
    uint2* fh   = (uint2*)((char*)d_ws + (size_t)NGRID * sizeof(int)
                           + (size_t)KK * 4 * COUT * sizeof(uint4));

    // dense index grid: fill with -1, then scatter voxel ids
    hipMemsetAsync(grid, 0xFF, (size_t)NGRID * sizeof(int), stream);
    scatter_grid<<<(n + 255) / 256, 256, 0, stream>>>((const int4*)coors, grid, n);

    pack_weights<<<(KK*4*COUT + 255) / 256, 256, 0, stream>>>(weight, wpk);
    feats_to_h<<<(n * CIN / 4 + 255) / 256, 256, 0, stream>>>((const float4*)feats, fh, n * CIN / 4);

    const size_t lds = (size_t)KK * 4 * COUT * sizeof(uint4);  // 110,592 B
    sparse_conv<<<NBLOCKS, BLOCK, lds, stream>>>((const uint4*)fh, (const int4*)coors,
                                                 bias, wpk, grid, outp, n);
}